// Round 4
// baseline (110.418 us; speedup 1.0000x reference)
//
#include <hip/hip_runtime.h>
#include <stdint.h>

// DEQ: z_{t+1} = tanh(c + z_t @ B_w^T), c = x@A_w^T + A_b + B_b (fp32, computed once).
// ||B_w||_2 ~= 0.115 -> contraction; 5 Picard applications converge to ~6e-6 in y.
//
// Transposed MFMA 16x16x16_f16 (r1 layout identity, verified): B-operand layout
// (k=quad*4+j, n=lane&15) == C/D layout (row=quad*4+r, col=lane&15), so
// tanh(acc)+cvt_pkrtz written state-contiguous IS the next B-fragment.
//
// r3 post-mortem: 4 structurally different kernels all land at 52us; occupancy
// pinned ~33% despite resources allowing ~100% -> stall-weighted occupancy,
// per-app serial chain (ds_read -> 8-dep MFMA -> tanh -> barrier) exposed.
//
// THIS ROUND: chain-exposure attack, math unchanged.
//  1. All blocks co-resident: grid=1024 (4 blocks/CU by 34.8KB LDS), each block
//     loops niter=2 batch-tiles -> zero block-round serialization.
//  2. 64 batch/block as TWO independent 32-batch groups: 8 independent MFMA
//     chains per barrier window; group B fills group A's latency shadow;
//     barriers per unit batch halved.
//  3. af/hw/h_b loaded once per block (setup was ~25% of block time; B_w L2
//     traffic 4096->1024 x 64KB).

typedef _Float16 half4  __attribute__((ext_vector_type(4)));
typedef __fp16   fp16x2 __attribute__((ext_vector_type(2)));  // cvt_pkrtz native type
typedef float    f32x4  __attribute__((ext_vector_type(4)));

#define ZS 132   // f16 per z-row: 128 states + 4 pad (264B rows; 0 conflicts measured r3)

union H2U { fp16x2 h; uint32_t u; };
union H4U { half4 h; uint32_t u[2]; };

__device__ __forceinline__ float tanh_fast(float v) {
    // tanh(v) = 1 - 2/(e^{2v}+1); v_exp_f32 + v_rcp_f32 (~1 ulp each)
    float e2 = __builtin_amdgcn_exp2f(v * 2.8853900817779268f); // 2*log2(e)
    return 1.0f - 2.0f * __builtin_amdgcn_rcpf(e2 + 1.0f);
}

__global__ __launch_bounds__(256, 4)
void deq_solve_kernel(const float* __restrict__ xin,
                      const float* __restrict__ A_w,
                      const float* __restrict__ A_b,
                      const float* __restrict__ B_w,
                      const float* __restrict__ B_b,
                      const float* __restrict__ h_w,
                      const float* __restrict__ h_b,
                      float* __restrict__ out,
                      int niter)
{
    __shared__ __align__(16) _Float16 zex[2][64 * ZS];  // ping-pong z, [batch 64][state]
    __shared__ float red[4][64];                        // cross-wave output reduction

    const int tid  = threadIdx.x;
    const int lane = tid & 63;
    const int wv   = tid >> 6;       // wave owns states [32*wv, 32*wv+32)
    const int quad = lane >> 4;
    const int bcol = lane & 15;

    // ---- once per block: af(mt,kt) = B_w[32wv+16mt+bcol][16kt+4quad+j] (f32->f16,
    //      direct from global, L2-resident; 32 VGPRs) ----
    half4 af[2][8];
    #pragma unroll
    for (int mt = 0; mt < 2; ++mt) {
        const f32x4* rowp = (const f32x4*)(B_w + (wv * 32 + mt * 16 + bcol) * 128 + quad * 4);
        #pragma unroll
        for (int kt = 0; kt < 8; ++kt) {
            f32x4 v = rowp[kt * 4];
            H2U a, b; H4U w;
            a.h = __builtin_amdgcn_cvt_pkrtz(v[0], v[1]);
            b.h = __builtin_amdgcn_cvt_pkrtz(v[2], v[3]);
            w.u[0] = a.u; w.u[1] = b.u;
            af[mt][kt] = w.h;
        }
    }
    // once per block: output weights for own states + h_b
    f32x4 hw[2];
    #pragma unroll
    for (int mt = 0; mt < 2; ++mt)
        hw[mt] = *(const f32x4*)(h_w + wv * 32 + mt * 16 + quad * 4);
    const float hb0 = h_b[0];

    // tanh + pack + write group-G state-slice to zex[BUF] (state-contiguous b64)
#define EPILOGUE_G(ACC, G, BUF)                                                \
    _Pragma("unroll")                                                          \
    for (int mt = 0; mt < 2; ++mt)                                             \
        _Pragma("unroll")                                                      \
        for (int nt = 0; nt < 2; ++nt) {                                       \
            H2U pa, pb; H4U w;                                                 \
            pa.h = __builtin_amdgcn_cvt_pkrtz(tanh_fast((ACC)[mt][nt][0]),     \
                                              tanh_fast((ACC)[mt][nt][1]));    \
            pb.h = __builtin_amdgcn_cvt_pkrtz(tanh_fast((ACC)[mt][nt][2]),     \
                                              tanh_fast((ACC)[mt][nt][3]));    \
            w.u[0] = pa.u; w.u[1] = pb.u;                                      \
            *(half4*)(&zex[BUF][((G) * 32 + nt * 16 + bcol) * ZS               \
                                + wv * 32 + mt * 16 + quad * 4]) = w.h;        \
        }

    // load full-state B-fragments for group G and run the 8-step MFMA chain
#define APP_G(G, RBUF, ACC)                                                    \
    {                                                                          \
        half4 bf[8][2];                                                        \
        _Pragma("unroll")                                                      \
        for (int kt = 0; kt < 8; ++kt)                                         \
            _Pragma("unroll")                                                  \
            for (int nt = 0; nt < 2; ++nt)                                     \
                bf[kt][nt] = *(const half4*)(&zex[RBUF][((G) * 32 + nt * 16 + bcol) * ZS \
                                                        + kt * 16 + quad * 4]); \
        _Pragma("unroll")                                                      \
        for (int mt = 0; mt < 2; ++mt)                                         \
            _Pragma("unroll")                                                  \
            for (int nt = 0; nt < 2; ++nt)                                     \
                (ACC)[mt][nt] = __builtin_amdgcn_mfma_f32_16x16x16f16(         \
                    af[mt][0], bf[0][nt], cf[G][mt][nt], 0, 0, 0);             \
        _Pragma("unroll")                                                      \
        for (int kt = 1; kt < 8; ++kt)                                         \
            _Pragma("unroll")                                                  \
            for (int mt = 0; mt < 2; ++mt)                                     \
                _Pragma("unroll")                                              \
                for (int nt = 0; nt < 2; ++nt)                                 \
                    (ACC)[mt][nt] = __builtin_amdgcn_mfma_f32_16x16x16f16(     \
                        af[mt][kt], bf[kt][nt], (ACC)[mt][nt], 0, 0, 0);       \
    }

#define MIDAPP(RBUF, WBUF)                                                     \
    {                                                                          \
        f32x4 acc0[2][2], acc1[2][2];                                          \
        APP_G(0, RBUF, acc0)                                                   \
        EPILOGUE_G(acc0, 0, WBUF)                                              \
        APP_G(1, RBUF, acc1)                                                   \
        EPILOGUE_G(acc1, 1, WBUF)                                              \
        __syncthreads();                                                       \
    }

    for (int itb = 0; itb < niter; ++itb) {
        const int b0 = (blockIdx.x * niter + itb) * 64;

        // ---- cf[g][mt][nt]: c for state s=32wv+16mt+4quad+r, batch b0+32g+16nt+bcol
        f32x4 xv[2][2];
        #pragma unroll
        for (int g = 0; g < 2; ++g)
            #pragma unroll
            for (int nt = 0; nt < 2; ++nt)
                xv[g][nt] = *(const f32x4*)(xin + 4 * (b0 + g * 32 + nt * 16 + bcol));
        f32x4 cf[2][2][2];
        #pragma unroll
        for (int mt = 0; mt < 2; ++mt) {
            #pragma unroll
            for (int r = 0; r < 4; ++r) {
                int s = wv * 32 + mt * 16 + quad * 4 + r;
                f32x4 aw = *(const f32x4*)(A_w + 4 * s);
                float bias = A_b[s] + B_b[s];
                #pragma unroll
                for (int g = 0; g < 2; ++g)
                    #pragma unroll
                    for (int nt = 0; nt < 2; ++nt)
                        cf[g][mt][nt][r] = bias + aw[0]*xv[g][nt][0] + aw[1]*xv[g][nt][1]
                                                + aw[2]*xv[g][nt][2] + aw[3]*xv[g][nt][3];
            }
        }

        // ---- application 1: z1 = tanh(c) ----
        EPILOGUE_G(cf[0], 0, 0)
        EPILOGUE_G(cf[1], 1, 0)
        __syncthreads();

        // ---- applications 2..4 (ping-pong; one barrier per app) ----
        MIDAPP(0, 1)
        MIDAPP(1, 0)
        MIDAPP(0, 1)

        // ---- application 5 fused with output: y = h_w . tanh(acc) + h_b ----
        float p00 = 0.f, p01 = 0.f, p10 = 0.f, p11 = 0.f;
        {
            f32x4 acc[2][2];
            APP_G(0, 1, acc)
            #pragma unroll
            for (int mt = 0; mt < 2; ++mt)
                #pragma unroll
                for (int r = 0; r < 4; ++r) {
                    p00 += tanh_fast(acc[mt][0][r]) * hw[mt][r];
                    p01 += tanh_fast(acc[mt][1][r]) * hw[mt][r];
                }
        }
        {
            f32x4 acc[2][2];
            APP_G(1, 1, acc)
            #pragma unroll
            for (int mt = 0; mt < 2; ++mt)
                #pragma unroll
                for (int r = 0; r < 4; ++r) {
                    p10 += tanh_fast(acc[mt][0][r]) * hw[mt][r];
                    p11 += tanh_fast(acc[mt][1][r]) * hw[mt][r];
                }
        }
        // reduce over the 4 quads -> every lane holds the wave's 4 partials
        p00 += __shfl_xor(p00, 16); p00 += __shfl_xor(p00, 32);
        p01 += __shfl_xor(p01, 16); p01 += __shfl_xor(p01, 32);
        p10 += __shfl_xor(p10, 16); p10 += __shfl_xor(p10, 32);
        p11 += __shfl_xor(p11, 16); p11 += __shfl_xor(p11, 32);
        // lane -> batch element: bit4 = nt, bit5 = g
        float vlo = (lane & 16) ? p01 : p00;
        float vhi = (lane & 16) ? p11 : p10;
        red[wv][lane] = (lane & 32) ? vhi : vlo;
        __syncthreads();
        if (tid < 64)
            out[b0 + tid] = red[0][tid] + red[1][tid] + red[2][tid] + red[3][tid] + hb0;
        // next iteration's zex[0] writes are safe: zex[0] last read before app4's
        // barrier; red next written only after the next iteration's barriers.
    }
}

extern "C" void kernel_launch(void* const* d_in, const int* in_sizes, int n_in,
                              void* d_out, int out_size, void* d_ws, size_t ws_size,
                              hipStream_t stream) {
    const float* x   = (const float*)d_in[0];
    const float* A_w = (const float*)d_in[1];
    const float* A_b = (const float*)d_in[2];
    const float* B_w = (const float*)d_in[3];
    const float* B_b = (const float*)d_in[4];
    const float* h_w = (const float*)d_in[5];
    const float* h_b = (const float*)d_in[6];
    float* outp = (float*)d_out;

    int batch = in_sizes[0] / 4;        // 131072
    int grid  = 1024;                   // 4 blocks/CU x 256 CUs, all co-resident
    int niter = batch / (grid * 64);    // 2 batch-tiles of 64 per block
    deq_solve_kernel<<<grid, 256, 0, stream>>>(x, A_w, A_b, B_w, B_b, h_w, h_b, outp, niter);
}